// Round 16
// baseline (272.139 us; speedup 1.0000x reference)
//
#include <hip/hip_runtime.h>
#include <hip/hip_bf16.h>
#include <math.h>

#define Bn   8
#define Ln   4096
#define DINn 128
#define Hn   256
#define N2n  8
#define NLn  4
#define NP   4   // mode pairs

typedef __attribute__((ext_vector_type(4))) float f32x4;
typedef __attribute__((ext_vector_type(2))) float f32x2;
typedef __attribute__((ext_vector_type(8))) short bf16x8;

__device__ __forceinline__ float gelu_f(float x) {
    float x2 = x * x;
    float inner = 0.7978845608028654f * x * fmaf(0.044715f, x2, 1.0f);
    float e = __expf(2.0f * inner);
    float th = 1.0f - 2.0f / (e + 1.0f);
    return 0.5f * x * (1.0f + th);
}

__device__ __forceinline__ float sigmoid_f(float x) {
    return 1.0f / (1.0f + __expf(-x));
}

__device__ __forceinline__ unsigned short f2bf(float f) {
    union { __hip_bfloat16 b; unsigned short u; } cv;
    cv.b = __float2bfloat16(f);
    return cv.u;
}

__device__ __forceinline__ uint4 pack8(float4 a, float4 b) {
    uint4 v;
    v.x = (unsigned)f2bf(a.x) | ((unsigned)f2bf(a.y) << 16);
    v.y = (unsigned)f2bf(a.z) | ((unsigned)f2bf(a.w) << 16);
    v.z = (unsigned)f2bf(b.x) | ((unsigned)f2bf(b.y) << 16);
    v.w = (unsigned)f2bf(b.z) | ((unsigned)f2bf(b.w) << 16);
    return v;
}

#define PKFMA(a, b, c) __builtin_elementwise_fma((f32x2)(a), (f32x2)(b), (f32x2)(c))

// ---------------------------------------------------------------------------
// S4D scan — byte-identical to round 15 (passing, packed f32x2 math).
// ---------------------------------------------------------------------------
__global__ __launch_bounds__(256) void s4_scan_kernel(
    const float* __restrict__ hT,          // (B,H,L) f32
    unsigned short* __restrict__ yT,       // (B,H,L) bf16 out
    const float* __restrict__ log_dt,
    const float* __restrict__ log_A_real,
    const float* __restrict__ A_imag,
    const float* __restrict__ C_re,
    const float* __restrict__ C_im,
    const float* __restrict__ D_skip)
{
    __shared__ float u_lds[4][64][65];
    const int tid = threadIdx.x;
    const int v = tid >> 6;
    const int t = tid & 63;
    const int h = blockIdx.x * 4 + v;
    const int b = blockIdx.y;

    const size_t rowbase = (size_t)(b * Hn + h) * Ln + (size_t)t * 64;
    const float* src = hT + rowbase;
    float* uL = &u_lds[v][t][0];

    #pragma unroll
    for (int j4 = 0; j4 < 16; ++j4) {
        float4 g = *(const float4*)(src + j4 * 4);
        uL[j4 * 4 + 0] = g.x; uL[j4 * 4 + 1] = g.y;
        uL[j4 * 4 + 2] = g.z; uL[j4 * 4 + 3] = g.w;
    }

    float dt = expf(log_dt[h]);
    f32x2 wrp[NP], wip[NP], crp[NP], cip[NP];
    #pragma unroll
    for (int q = 0; q < NP; ++q) {
        #pragma unroll
        for (int e = 0; e < 2; ++e) {
            int n = 2 * q + e;
            float lar = log_A_real[h * N2n + n];
            float aim = A_imag[h * N2n + n];
            float are = -expf(lar);
            float mag = expf(are * dt);
            float s_, c_;
            sincosf(aim * dt, &s_, &c_);
            float w_re = mag * c_, w_im = mag * s_;
            float nre = w_re - 1.0f, nim = w_im;
            float inv = 1.0f / (are * are + aim * aim);
            float tre = (nre * are + nim * aim) * inv;
            float tim = (nim * are - nre * aim) * inv;
            float Cr = C_re[h * N2n + n], Ci = C_im[h * N2n + n];
            wrp[q][e] = w_re; wip[q][e] = w_im;
            crp[q][e] = Cr * tre - Ci * tim;
            cip[q][e] = Cr * tim + Ci * tre;
        }
    }
    const float Dsk = D_skip[h];

    f32x2 srp[NP], sip[NP];
    #pragma unroll
    for (int q = 0; q < NP; ++q) { srp[q] = (f32x2)0.0f; sip[q] = (f32x2)0.0f; }
    #pragma unroll 4
    for (int j = 0; j < 64; ++j) {
        float u = uL[j];
        f32x2 uu = { u, u };
        f32x2 accp = (f32x2)0.0f;
        #pragma unroll
        for (int q = 0; q < NP; ++q) {
            f32x2 nr = PKFMA(wrp[q], srp[q], PKFMA(-wip[q], sip[q], uu));
            f32x2 ni = PKFMA(wip[q], srp[q], wrp[q] * sip[q]);
            srp[q] = nr; sip[q] = ni;
            accp = PKFMA(crp[q], nr, PKFMA(-cip[q], ni, accp));
        }
        float acc = accp.x + accp.y;
        uL[j] = fmaf(2.0f, acc, Dsk * u);
    }

    f32x2 mrp[NP], mip[NP];
    #pragma unroll
    for (int q = 0; q < NP; ++q) {
        f32x2 ar = wrp[q], ai = wip[q];
        #pragma unroll
        for (int s = 0; s < 6; ++s) {
            f32x2 nr2 = ar * ar - ai * ai;
            ai = 2.0f * ar * ai;
            ar = nr2;
        }
        mrp[q] = ar; mip[q] = ai;   // w^64
    }
    for (int dlt = 1; dlt < 64; dlt <<= 1) {
        #pragma unroll
        for (int q = 0; q < NP; ++q) {
            f32x2 tr, ti;
            tr.x = __shfl_up(srp[q].x, (unsigned)dlt, 64);
            tr.y = __shfl_up(srp[q].y, (unsigned)dlt, 64);
            ti.x = __shfl_up(sip[q].x, (unsigned)dlt, 64);
            ti.y = __shfl_up(sip[q].y, (unsigned)dlt, 64);
            f32x2 trz = (t >= dlt) ? tr : (f32x2)0.0f;
            f32x2 tiz = (t >= dlt) ? ti : (f32x2)0.0f;
            srp[q] = PKFMA(mrp[q], trz, PKFMA(-mip[q], tiz, srp[q]));
            sip[q] = PKFMA(mrp[q], tiz, PKFMA(mip[q], trz, sip[q]));
        }
        #pragma unroll
        for (int q = 0; q < NP; ++q) {
            f32x2 nr2 = mrp[q] * mrp[q] - mip[q] * mip[q];
            mip[q] = 2.0f * mrp[q] * mip[q];
            mrp[q] = nr2;
        }
    }
    f32x2 prp[NP], pip[NP];
    #pragma unroll
    for (int q = 0; q < NP; ++q) {
        f32x2 er, ei;
        er.x = __shfl_up(srp[q].x, 1u, 64);
        er.y = __shfl_up(srp[q].y, 1u, 64);
        ei.x = __shfl_up(sip[q].x, 1u, 64);
        ei.y = __shfl_up(sip[q].y, 1u, 64);
        prp[q] = (t >= 1) ? er : (f32x2)0.0f;
        pip[q] = (t >= 1) ? ei : (f32x2)0.0f;
    }

    f32x2 dr2p[NP], di2p[NP];
    #pragma unroll
    for (int q = 0; q < NP; ++q) { dr2p[q] = crp[q]; di2p[q] = cip[q]; }
    unsigned short* dst = yT + rowbase;
    for (int j8 = 0; j8 < 8; ++j8) {
        unsigned short rs[8];
        #pragma unroll
        for (int c = 0; c < 8; ++c) {
            f32x2 corrp = (f32x2)0.0f;
            #pragma unroll
            for (int q = 0; q < NP; ++q) {
                f32x2 nr2 = dr2p[q] * wrp[q] - di2p[q] * wip[q];
                f32x2 ni2 = PKFMA(dr2p[q], wip[q], di2p[q] * wrp[q]);
                dr2p[q] = nr2; di2p[q] = ni2;
                corrp = PKFMA(nr2, prp[q], PKFMA(-ni2, pip[q], corrp));
            }
            float corr = corrp.x + corrp.y;
            float yv = fmaf(2.0f, corr, uL[j8 * 8 + c]);
            rs[c] = f2bf(gelu_f(yv));
        }
        uint4 o;
        o.x = (unsigned)rs[0] | ((unsigned)rs[1] << 16);
        o.y = (unsigned)rs[2] | ((unsigned)rs[3] << 16);
        o.z = (unsigned)rs[4] | ((unsigned)rs[5] << 16);
        o.w = (unsigned)rs[6] | ((unsigned)rs[7] << 16);
        *(uint4*)(dst + j8 * 8) = o;
    }
}

// ---------------------------------------------------------------------------
// MFMA GEMM, residual-in-hT edition + A-tile register prefetch (T14):
// tile kt+1's A global loads issue right after tile kt's LDS writes, so A's
// HBM latency hides under the barrier+MFMA phase.  B (L2-resident weights)
// stays synchronous.  Numerics identical to round 13/15.
// ---------------------------------------------------------------------------
template<int KDIM, bool GLU, bool ACVT, bool KMAJ, bool LAST>
__global__ __launch_bounds__(256) void mfma_gemm(
    const unsigned short* __restrict__ Abf,   // KMAJ: yT (B,H,L)
    const float* __restrict__ Af,             // ACVT: x (M,KDIM) f32
    const float* __restrict__ W,
    const float* __restrict__ ba,
    const float* __restrict__ bg,
    float* hTbuf,                             // (B,256,L) f32 residual stream
    float* Hout)                              // LAST only: (M,256) f32
{
    constexpr int SM_MAIN = 128 * 72 * 2 + (GLU ? 2 : 1) * 64 * 72 * 2;
    constexpr int SM_TS = 64 * 132 * 4;
    constexpr int SM = SM_MAIN > SM_TS ? SM_MAIN : SM_TS;
    constexpr int NKT = KDIM / 64;
    __shared__ __align__(16) char smem[SM];
    unsigned short* As  = (unsigned short*)smem;   // [128 rows][72]
    unsigned short* Bs0 = As + 128 * 72;           // [64][72]
    unsigned short* Bs1 = Bs0 + 64 * 72;           // GLU only
    float* ts = (float*)smem;                      // [64 n][132] reused

    const int tid = threadIdx.x;
    const int lane = tid & 63, w = tid >> 6;
    const int wm = w >> 1, wn = w & 1;
    const int lr = lane & 15, lq = lane >> 4;
    const int row0 = blockIdx.x * 128;
    const int n0 = blockIdx.y * 64;
    const int bb = row0 >> 12;
    const int l0 = row0 & (Ln - 1);

    f32x4 accA[4][2], accG[4][2];
    #pragma unroll
    for (int i = 0; i < 4; ++i)
        #pragma unroll
        for (int j = 0; j < 2; ++j) {
            accA[i][j] = (f32x4)0.0f;
            if constexpr (GLU) accG[i][j] = (f32x4)0.0f;
        }

    // A-tile prefetch registers
    uint4  rA[4];        // KMAJ
    float4 rAf[4][2];    // ACVT

    auto load_A = [&](int kt) {
        const int k0 = kt * 64;
        if constexpr (ACVT) {
            #pragma unroll
            for (int it = 0; it < 4; ++it) {
                int idx = it * 256 + tid; int m = idx >> 3, q = idx & 7;
                const float* s = Af + (size_t)(row0 + m) * KDIM + k0 + q * 8;
                rAf[it][0] = *(const float4*)s;
                rAf[it][1] = *(const float4*)(s + 4);
            }
        } else {
            #pragma unroll
            for (int it = 0; it < 4; ++it) {
                int p = tid >> 2;
                int c = (tid & 3) | (it << 2);
                rA[it] = *(const uint4*)(Abf + (size_t)(bb * Hn + k0 + p) * Ln + l0 + c * 8);
            }
        }
    };

    load_A(0);
    for (int kt = 0; kt < NKT; ++kt) {
        const int k0 = kt * 64;
        // ---- write prefetched A regs -> LDS ----
        if constexpr (ACVT) {
            #pragma unroll
            for (int it = 0; it < 4; ++it) {
                int idx = it * 256 + tid; int m = idx >> 3, q = idx & 7;
                *(uint4*)(&As[m * 72 + q * 8]) = pack8(rAf[it][0], rAf[it][1]);
            }
        } else {
            #pragma unroll
            for (int it = 0; it < 4; ++it) {
                int p = tid >> 2;
                int c = (tid & 3) | (it << 2);
                uint4 g = rA[it];
                unsigned short* d = &As[(c * 8) * 72 + p];
                d[0 * 72] = g.x & 0xffff; d[1 * 72] = g.x >> 16;
                d[2 * 72] = g.y & 0xffff; d[3 * 72] = g.y >> 16;
                d[4 * 72] = g.z & 0xffff; d[5 * 72] = g.z >> 16;
                d[6 * 72] = g.w & 0xffff; d[7 * 72] = g.w >> 16;
            }
        }
        // ---- issue next A-tile loads early (latency hides under MFMA) ----
        if (kt + 1 < NKT) load_A(kt + 1);
        // ---- stage B (synchronous; W is L2-resident) ----
        #pragma unroll
        for (int it = 0; it < 2; ++it) {
            int idx = it * 256 + tid; int p = idx >> 3, q = idx & 7;
            {
                const float* s = W + (size_t)(n0 + p) * KDIM + k0 + q * 8;
                float4 g1 = *(const float4*)s;
                float4 g2 = *(const float4*)(s + 4);
                *(uint4*)(&Bs0[p * 72 + q * 8]) = pack8(g1, g2);
            }
            if constexpr (GLU) {
                const float* s = W + (size_t)(256 + n0 + p) * KDIM + k0 + q * 8;
                float4 g1 = *(const float4*)s;
                float4 g2 = *(const float4*)(s + 4);
                *(uint4*)(&Bs1[p * 72 + q * 8]) = pack8(g1, g2);
            }
        }
        __syncthreads();
        #pragma unroll
        for (int kf = 0; kf < 2; ++kf) {
            bf16x8 av[4], bv[2], gv[2];
            #pragma unroll
            for (int mf = 0; mf < 4; ++mf)
                av[mf] = *(const bf16x8*)(&As[(wm * 64 + mf * 16 + lr) * 72 + (kf * 4 + lq) * 8]);
            #pragma unroll
            for (int nf = 0; nf < 2; ++nf) {
                bv[nf] = *(const bf16x8*)(&Bs0[(wn * 32 + nf * 16 + lr) * 72 + (kf * 4 + lq) * 8]);
                if constexpr (GLU)
                    gv[nf] = *(const bf16x8*)(&Bs1[(wn * 32 + nf * 16 + lr) * 72 + (kf * 4 + lq) * 8]);
            }
            #pragma unroll
            for (int mf = 0; mf < 4; ++mf)
                #pragma unroll
                for (int nf = 0; nf < 2; ++nf) {
                    accA[mf][nf] = __builtin_amdgcn_mfma_f32_16x16x32_bf16(av[mf], bv[nf], accA[mf][nf], 0, 0, 0);
                    if constexpr (GLU)
                        accG[mf][nf] = __builtin_amdgcn_mfma_f32_16x16x32_bf16(av[mf], gv[nf], accG[mf][nf], 0, 0, 0);
                }
        }
        __syncthreads();
    }

    // ---- epilogue pass 1: raw (bias + GLU) -> ts[n_loc][m_loc], pitch 132 ----
    float bA[2], bG[2];
    #pragma unroll
    for (int nf = 0; nf < 2; ++nf) {
        int pc = n0 + wn * 32 + nf * 16 + lr;
        bA[nf] = ba[pc];
        if constexpr (GLU) bG[nf] = bg[pc];
    }
    #pragma unroll
    for (int mf = 0; mf < 4; ++mf) {
        #pragma unroll
        for (int r = 0; r < 4; ++r) {
            int m_loc = wm * 64 + mf * 16 + lq * 4 + r;
            #pragma unroll
            for (int nf = 0; nf < 2; ++nf) {
                float val;
                if constexpr (GLU) {
                    float aval = accA[mf][nf][r] + bA[nf];
                    float gval = accG[mf][nf][r] + bG[nf];
                    val = aval * sigmoid_f(gval);
                } else {
                    val = accA[mf][nf][r] + bA[nf];
                }
                ts[(wn * 32 + nf * 16 + lr) * 132 + m_loc] = val;
            }
        }
    }
    __syncthreads();

    if constexpr (!LAST) {
        #pragma unroll
        for (int it2 = 0; it2 < 8; ++it2) {
            int idx = it2 * 256 + tid;
            int nn = idx >> 5, m4 = (idx & 31) * 4;
            float4 o = *(const float4*)(&ts[nn * 132 + m4]);
            float* gp = hTbuf + (size_t)(bb * Hn + n0 + nn) * Ln + l0 + m4;
            if constexpr (GLU) {
                float4 rr = *(const float4*)gp;
                o.x += rr.x; o.y += rr.y; o.z += rr.z; o.w += rr.w;
            }
            *(float4*)gp = o;
        }
    } else {
        #pragma unroll
        for (int it2 = 0; it2 < 8; ++it2) {
            int idx = it2 * 256 + tid;
            int nn = idx >> 5, m4 = (idx & 31) * 4;
            float4 o = *(const float4*)(&ts[nn * 132 + m4]);
            const float* gp = hTbuf + (size_t)(bb * Hn + n0 + nn) * Ln + l0 + m4;
            float4 rr = *(const float4*)gp;
            o.x += rr.x; o.y += rr.y; o.z += rr.z; o.w += rr.w;
            *(float4*)(&ts[nn * 132 + m4]) = o;
        }
        __syncthreads();
        #pragma unroll
        for (int it2 = 0; it2 < 8; ++it2) {
            int idx = it2 * 256 + tid;
            int m = idx >> 4, n4 = (idx & 15) * 4;
            float4 o;
            o.x = ts[(n4 + 0) * 132 + m];
            o.y = ts[(n4 + 1) * 132 + m];
            o.z = ts[(n4 + 2) * 132 + m];
            o.w = ts[(n4 + 3) * 132 + m];
            *(float4*)(Hout + (size_t)(row0 + m) * Hn + n0 + n4) = o;
        }
    }
}

extern "C" void kernel_launch(void* const* d_in, const int* in_sizes, int n_in,
                              void* d_out, int out_size, void* d_ws, size_t ws_size,
                              hipStream_t stream) {
    (void)in_sizes; (void)n_in; (void)out_size; (void)ws_size;
    const float* x          = (const float*)d_in[0];
    const float* enc_w      = (const float*)d_in[1];
    const float* enc_b      = (const float*)d_in[2];
    const float* log_dt     = (const float*)d_in[3];
    const float* log_A_real = (const float*)d_in[4];
    const float* A_imag     = (const float*)d_in[5];
    const float* C_re       = (const float*)d_in[6];
    const float* C_im       = (const float*)d_in[7];
    const float* D_skip     = (const float*)d_in[8];
    const float* out_w      = (const float*)d_in[9];
    const float* out_b      = (const float*)d_in[10];

    const size_t NE = (size_t)Bn * Hn * Ln;
    float* h  = (float*)d_out;                        // (B,L,H) final output only
    float* hT = (float*)d_ws;                         // (B,256,L) f32 residual stream
    unsigned short* yT = (unsigned short*)(hT + NE);  // (B,H,L) bf16 scan output

    const dim3 gg(256, 4), gb(256);

    // encoder: hT = (x @ enc_w^T + enc_b)^T
    mfma_gemm<DINn, false, true, false, false><<<gg, gb, 0, stream>>>(
        nullptr, x, enc_w, enc_b, nullptr, hT, nullptr);

    for (int i = 0; i < NLn; ++i) {
        s4_scan_kernel<<<dim3(Hn / 4, Bn), gb, 0, stream>>>(
            hT, yT,
            log_dt + (size_t)i * Hn,
            log_A_real + (size_t)i * Hn * N2n,
            A_imag + (size_t)i * Hn * N2n,
            C_re + (size_t)i * Hn * N2n,
            C_im + (size_t)i * Hn * N2n,
            D_skip + (size_t)i * Hn);
        const float* wlay = out_w + (size_t)i * 2 * Hn * Hn;
        const float* bl = out_b + (size_t)i * 2 * Hn;
        if (i == NLn - 1) {
            mfma_gemm<Hn, true, false, true, true><<<gg, gb, 0, stream>>>(
                yT, nullptr, wlay, bl, bl + Hn, hT, h);
        } else {
            mfma_gemm<Hn, true, false, true, false><<<gg, gb, 0, stream>>>(
                yT, nullptr, wlay, bl, bl + Hn, hT, nullptr);
        }
    }
}

// Round 17
// 257.761 us; speedup vs baseline: 1.0558x; 1.0558x over previous
//
#include <hip/hip_runtime.h>
#include <hip/hip_bf16.h>
#include <math.h>

#define Bn   8
#define Ln   4096
#define DINn 128
#define Hn   256
#define N2n  8
#define NLn  4
#define NP   4   // mode pairs

typedef __attribute__((ext_vector_type(4))) float f32x4;
typedef __attribute__((ext_vector_type(2))) float f32x2;
typedef __attribute__((ext_vector_type(8))) short bf16x8;

__device__ __forceinline__ float gelu_f(float x) {
    float x2 = x * x;
    float inner = 0.7978845608028654f * x * fmaf(0.044715f, x2, 1.0f);
    float e = __expf(2.0f * inner);
    float th = 1.0f - 2.0f / (e + 1.0f);
    return 0.5f * x * (1.0f + th);
}

__device__ __forceinline__ float sigmoid_f(float x) {
    return 1.0f / (1.0f + __expf(-x));
}

__device__ __forceinline__ unsigned short f2bf(float f) {
    union { __hip_bfloat16 b; unsigned short u; } cv;
    cv.b = __float2bfloat16(f);
    return cv.u;
}

__device__ __forceinline__ uint4 pack8(float4 a, float4 b) {
    uint4 v;
    v.x = (unsigned)f2bf(a.x) | ((unsigned)f2bf(a.y) << 16);
    v.y = (unsigned)f2bf(a.z) | ((unsigned)f2bf(a.w) << 16);
    v.z = (unsigned)f2bf(b.x) | ((unsigned)f2bf(b.y) << 16);
    v.w = (unsigned)f2bf(b.z) | ((unsigned)f2bf(b.w) << 16);
    return v;
}

#define PKFMA(a, b, c) __builtin_elementwise_fma((f32x2)(a), (f32x2)(b), (f32x2)(c))

// ---------------------------------------------------------------------------
// S4D scan — r15 packed-f32 version, restructured to the r4-validated
// two-pass form: phase 1 state-only (4 pk-ops/pair/elem), phase 3 = full
// recurrence from the KS-corrected incoming state with projection + D-skip
// + gelu fused (6 ops).  u stays untouched in LDS (read twice, no write-back).
// grid (H/4, B), block 256 = 4 independent waves.
// ---------------------------------------------------------------------------
__global__ __launch_bounds__(256) void s4_scan_kernel(
    const float* __restrict__ hT,          // (B,H,L) f32
    unsigned short* __restrict__ yT,       // (B,H,L) bf16 out
    const float* __restrict__ log_dt,
    const float* __restrict__ log_A_real,
    const float* __restrict__ A_imag,
    const float* __restrict__ C_re,
    const float* __restrict__ C_im,
    const float* __restrict__ D_skip)
{
    __shared__ float u_lds[4][64][65];
    const int tid = threadIdx.x;
    const int v = tid >> 6;
    const int t = tid & 63;
    const int h = blockIdx.x * 4 + v;
    const int b = blockIdx.y;

    const size_t rowbase = (size_t)(b * Hn + h) * Ln + (size_t)t * 64;
    const float* src = hT + rowbase;
    float* uL = &u_lds[v][t][0];

    #pragma unroll
    for (int j4 = 0; j4 < 16; ++j4) {
        float4 g = *(const float4*)(src + j4 * 4);
        uL[j4 * 4 + 0] = g.x; uL[j4 * 4 + 1] = g.y;
        uL[j4 * 4 + 2] = g.z; uL[j4 * 4 + 3] = g.w;
    }

    float dt = expf(log_dt[h]);
    f32x2 wrp[NP], wip[NP], crp[NP], cip[NP];
    #pragma unroll
    for (int q = 0; q < NP; ++q) {
        #pragma unroll
        for (int e = 0; e < 2; ++e) {
            int n = 2 * q + e;
            float lar = log_A_real[h * N2n + n];
            float aim = A_imag[h * N2n + n];
            float are = -expf(lar);
            float mag = expf(are * dt);
            float s_, c_;
            sincosf(aim * dt, &s_, &c_);
            float w_re = mag * c_, w_im = mag * s_;
            float nre = w_re - 1.0f, nim = w_im;
            float inv = 1.0f / (are * are + aim * aim);
            float tre = (nre * are + nim * aim) * inv;
            float tim = (nim * are - nre * aim) * inv;
            float Cr = C_re[h * N2n + n], Ci = C_im[h * N2n + n];
            wrp[q][e] = w_re; wip[q][e] = w_im;
            crp[q][e] = Cr * tre - Ci * tim;
            cip[q][e] = Cr * tim + Ci * tre;
        }
    }
    const float Dsk = D_skip[h];

    // ---- phase 1: state-only local scan (no projection, no LDS write) ----
    f32x2 srp[NP], sip[NP];
    #pragma unroll
    for (int q = 0; q < NP; ++q) { srp[q] = (f32x2)0.0f; sip[q] = (f32x2)0.0f; }
    #pragma unroll 4
    for (int j = 0; j < 64; ++j) {
        float u = uL[j];
        f32x2 uu = { u, u };
        #pragma unroll
        for (int q = 0; q < NP; ++q) {
            f32x2 nr = PKFMA(wrp[q], srp[q], PKFMA(-wip[q], sip[q], uu));
            f32x2 ni = PKFMA(wip[q], srp[q], wrp[q] * sip[q]);
            srp[q] = nr; sip[q] = ni;
        }
    }

    // ---- phase 2: inclusive wave scan of end-states, multiplier w^64 ----
    f32x2 mrp[NP], mip[NP];
    #pragma unroll
    for (int q = 0; q < NP; ++q) {
        f32x2 ar = wrp[q], ai = wip[q];
        #pragma unroll
        for (int s = 0; s < 6; ++s) {
            f32x2 nr2 = ar * ar - ai * ai;
            ai = 2.0f * ar * ai;
            ar = nr2;
        }
        mrp[q] = ar; mip[q] = ai;   // w^64
    }
    for (int dlt = 1; dlt < 64; dlt <<= 1) {
        #pragma unroll
        for (int q = 0; q < NP; ++q) {
            f32x2 tr, ti;
            tr.x = __shfl_up(srp[q].x, (unsigned)dlt, 64);
            tr.y = __shfl_up(srp[q].y, (unsigned)dlt, 64);
            ti.x = __shfl_up(sip[q].x, (unsigned)dlt, 64);
            ti.y = __shfl_up(sip[q].y, (unsigned)dlt, 64);
            f32x2 trz = (t >= dlt) ? tr : (f32x2)0.0f;
            f32x2 tiz = (t >= dlt) ? ti : (f32x2)0.0f;
            srp[q] = PKFMA(mrp[q], trz, PKFMA(-mip[q], tiz, srp[q]));
            sip[q] = PKFMA(mrp[q], tiz, PKFMA(mip[q], trz, sip[q]));
        }
        #pragma unroll
        for (int q = 0; q < NP; ++q) {
            f32x2 nr2 = mrp[q] * mrp[q] - mip[q] * mip[q];
            mip[q] = 2.0f * mrp[q] * mip[q];
            mrp[q] = nr2;
        }
    }
    // exclusive prefix = incoming state for this lane's chunk
    #pragma unroll
    for (int q = 0; q < NP; ++q) {
        f32x2 er, ei;
        er.x = __shfl_up(srp[q].x, 1u, 64);
        er.y = __shfl_up(srp[q].y, 1u, 64);
        ei.x = __shfl_up(sip[q].x, 1u, 64);
        ei.y = __shfl_up(sip[q].y, 1u, 64);
        srp[q] = (t >= 1) ? er : (f32x2)0.0f;
        sip[q] = (t >= 1) ? ei : (f32x2)0.0f;
    }

    // ---- phase 3: recurrence from corrected state + projection + gelu ----
    unsigned short* dst = yT + rowbase;
    for (int j8 = 0; j8 < 8; ++j8) {
        unsigned short rs[8];
        #pragma unroll
        for (int c = 0; c < 8; ++c) {
            float u = uL[j8 * 8 + c];
            f32x2 uu = { u, u };
            f32x2 accp = (f32x2)0.0f;
            #pragma unroll
            for (int q = 0; q < NP; ++q) {
                f32x2 nr = PKFMA(wrp[q], srp[q], PKFMA(-wip[q], sip[q], uu));
                f32x2 ni = PKFMA(wip[q], srp[q], wrp[q] * sip[q]);
                srp[q] = nr; sip[q] = ni;
                accp = PKFMA(crp[q], nr, PKFMA(-cip[q], ni, accp));
            }
            float acc = accp.x + accp.y;
            float yv = fmaf(2.0f, acc, Dsk * u);
            rs[c] = f2bf(gelu_f(yv));
        }
        uint4 o;
        o.x = (unsigned)rs[0] | ((unsigned)rs[1] << 16);
        o.y = (unsigned)rs[2] | ((unsigned)rs[3] << 16);
        o.z = (unsigned)rs[4] | ((unsigned)rs[5] << 16);
        o.w = (unsigned)rs[6] | ((unsigned)rs[7] << 16);
        *(uint4*)(dst + j8 * 8) = o;
    }
}

// ---------------------------------------------------------------------------
// MFMA GEMM, residual-in-hT edition (byte-identical to round 13/15).
// ---------------------------------------------------------------------------
template<int KDIM, bool GLU, bool ACVT, bool KMAJ, bool LAST>
__global__ __launch_bounds__(256) void mfma_gemm(
    const unsigned short* __restrict__ Abf,   // KMAJ: yT (B,H,L)
    const float* __restrict__ Af,             // ACVT: x (M,KDIM) f32
    const float* __restrict__ W,
    const float* __restrict__ ba,
    const float* __restrict__ bg,
    float* hTbuf,                             // (B,256,L) f32 residual stream
    float* Hout)                              // LAST only: (M,256) f32
{
    constexpr int SM_MAIN = 128 * 72 * 2 + (GLU ? 2 : 1) * 64 * 72 * 2;
    constexpr int SM_TS = 64 * 132 * 4;
    constexpr int SM = SM_MAIN > SM_TS ? SM_MAIN : SM_TS;
    __shared__ __align__(16) char smem[SM];
    unsigned short* As  = (unsigned short*)smem;   // [128 rows][72]
    unsigned short* Bs0 = As + 128 * 72;           // [64][72]
    unsigned short* Bs1 = Bs0 + 64 * 72;           // GLU only
    float* ts = (float*)smem;                      // [64 n][132] reused

    const int tid = threadIdx.x;
    const int lane = tid & 63, w = tid >> 6;
    const int wm = w >> 1, wn = w & 1;
    const int lr = lane & 15, lq = lane >> 4;
    const int row0 = blockIdx.x * 128;
    const int n0 = blockIdx.y * 64;
    const int bb = row0 >> 12;
    const int l0 = row0 & (Ln - 1);

    f32x4 accA[4][2], accG[4][2];
    #pragma unroll
    for (int i = 0; i < 4; ++i)
        #pragma unroll
        for (int j = 0; j < 2; ++j) {
            accA[i][j] = (f32x4)0.0f;
            if constexpr (GLU) accG[i][j] = (f32x4)0.0f;
        }

    for (int kt = 0; kt < KDIM / 64; ++kt) {
        const int k0 = kt * 64;
        if constexpr (ACVT) {
            #pragma unroll
            for (int it = 0; it < 4; ++it) {
                int idx = it * 256 + tid; int m = idx >> 3, q = idx & 7;
                const float* s = Af + (size_t)(row0 + m) * KDIM + k0 + q * 8;
                float4 g1 = *(const float4*)s;
                float4 g2 = *(const float4*)(s + 4);
                *(uint4*)(&As[m * 72 + q * 8]) = pack8(g1, g2);
            }
        } else {
            #pragma unroll
            for (int it = 0; it < 4; ++it) {
                int p = tid >> 2;
                int c = (tid & 3) | (it << 2);
                uint4 g = *(const uint4*)(Abf + (size_t)(bb * Hn + k0 + p) * Ln + l0 + c * 8);
                unsigned short* d = &As[(c * 8) * 72 + p];
                d[0 * 72] = g.x & 0xffff; d[1 * 72] = g.x >> 16;
                d[2 * 72] = g.y & 0xffff; d[3 * 72] = g.y >> 16;
                d[4 * 72] = g.z & 0xffff; d[5 * 72] = g.z >> 16;
                d[6 * 72] = g.w & 0xffff; d[7 * 72] = g.w >> 16;
            }
        }
        #pragma unroll
        for (int it = 0; it < 2; ++it) {
            int idx = it * 256 + tid; int p = idx >> 3, q = idx & 7;
            {
                const float* s = W + (size_t)(n0 + p) * KDIM + k0 + q * 8;
                float4 g1 = *(const float4*)s;
                float4 g2 = *(const float4*)(s + 4);
                *(uint4*)(&Bs0[p * 72 + q * 8]) = pack8(g1, g2);
            }
            if constexpr (GLU) {
                const float* s = W + (size_t)(256 + n0 + p) * KDIM + k0 + q * 8;
                float4 g1 = *(const float4*)s;
                float4 g2 = *(const float4*)(s + 4);
                *(uint4*)(&Bs1[p * 72 + q * 8]) = pack8(g1, g2);
            }
        }
        __syncthreads();
        #pragma unroll
        for (int kf = 0; kf < 2; ++kf) {
            bf16x8 av[4], bv[2], gv[2];
            #pragma unroll
            for (int mf = 0; mf < 4; ++mf)
                av[mf] = *(const bf16x8*)(&As[(wm * 64 + mf * 16 + lr) * 72 + (kf * 4 + lq) * 8]);
            #pragma unroll
            for (int nf = 0; nf < 2; ++nf) {
                bv[nf] = *(const bf16x8*)(&Bs0[(wn * 32 + nf * 16 + lr) * 72 + (kf * 4 + lq) * 8]);
                if constexpr (GLU)
                    gv[nf] = *(const bf16x8*)(&Bs1[(wn * 32 + nf * 16 + lr) * 72 + (kf * 4 + lq) * 8]);
            }
            #pragma unroll
            for (int mf = 0; mf < 4; ++mf)
                #pragma unroll
                for (int nf = 0; nf < 2; ++nf) {
                    accA[mf][nf] = __builtin_amdgcn_mfma_f32_16x16x32_bf16(av[mf], bv[nf], accA[mf][nf], 0, 0, 0);
                    if constexpr (GLU)
                        accG[mf][nf] = __builtin_amdgcn_mfma_f32_16x16x32_bf16(av[mf], gv[nf], accG[mf][nf], 0, 0, 0);
                }
        }
        __syncthreads();
    }

    // ---- epilogue pass 1: raw (bias + GLU) -> ts[n_loc][m_loc], pitch 132 ----
    float bA[2], bG[2];
    #pragma unroll
    for (int nf = 0; nf < 2; ++nf) {
        int pc = n0 + wn * 32 + nf * 16 + lr;
        bA[nf] = ba[pc];
        if constexpr (GLU) bG[nf] = bg[pc];
    }
    #pragma unroll
    for (int mf = 0; mf < 4; ++mf) {
        #pragma unroll
        for (int r = 0; r < 4; ++r) {
            int m_loc = wm * 64 + mf * 16 + lq * 4 + r;
            #pragma unroll
            for (int nf = 0; nf < 2; ++nf) {
                float val;
                if constexpr (GLU) {
                    float aval = accA[mf][nf][r] + bA[nf];
                    float gval = accG[mf][nf][r] + bG[nf];
                    val = aval * sigmoid_f(gval);
                } else {
                    val = accA[mf][nf][r] + bA[nf];
                }
                ts[(wn * 32 + nf * 16 + lr) * 132 + m_loc] = val;
            }
        }
    }
    __syncthreads();

    if constexpr (!LAST) {
        #pragma unroll
        for (int it2 = 0; it2 < 8; ++it2) {
            int idx = it2 * 256 + tid;
            int nn = idx >> 5, m4 = (idx & 31) * 4;
            float4 o = *(const float4*)(&ts[nn * 132 + m4]);
            float* gp = hTbuf + (size_t)(bb * Hn + n0 + nn) * Ln + l0 + m4;
            if constexpr (GLU) {
                float4 rr = *(const float4*)gp;
                o.x += rr.x; o.y += rr.y; o.z += rr.z; o.w += rr.w;
            }
            *(float4*)gp = o;
        }
    } else {
        #pragma unroll
        for (int it2 = 0; it2 < 8; ++it2) {
            int idx = it2 * 256 + tid;
            int nn = idx >> 5, m4 = (idx & 31) * 4;
            float4 o = *(const float4*)(&ts[nn * 132 + m4]);
            const float* gp = hTbuf + (size_t)(bb * Hn + n0 + nn) * Ln + l0 + m4;
            float4 rr = *(const float4*)gp;
            o.x += rr.x; o.y += rr.y; o.z += rr.z; o.w += rr.w;
            *(float4*)(&ts[nn * 132 + m4]) = o;
        }
        __syncthreads();
        #pragma unroll
        for (int it2 = 0; it2 < 8; ++it2) {
            int idx = it2 * 256 + tid;
            int m = idx >> 4, n4 = (idx & 15) * 4;
            float4 o;
            o.x = ts[(n4 + 0) * 132 + m];
            o.y = ts[(n4 + 1) * 132 + m];
            o.z = ts[(n4 + 2) * 132 + m];
            o.w = ts[(n4 + 3) * 132 + m];
            *(float4*)(Hout + (size_t)(row0 + m) * Hn + n0 + n4) = o;
        }
    }
}

extern "C" void kernel_launch(void* const* d_in, const int* in_sizes, int n_in,
                              void* d_out, int out_size, void* d_ws, size_t ws_size,
                              hipStream_t stream) {
    (void)in_sizes; (void)n_in; (void)out_size; (void)ws_size;
    const float* x          = (const float*)d_in[0];
    const float* enc_w      = (const float*)d_in[1];
    const float* enc_b      = (const float*)d_in[2];
    const float* log_dt     = (const float*)d_in[3];
    const float* log_A_real = (const float*)d_in[4];
    const float* A_imag     = (const float*)d_in[5];
    const float* C_re       = (const float*)d_in[6];
    const float* C_im       = (const float*)d_in[7];
    const float* D_skip     = (const float*)d_in[8];
    const float* out_w      = (const float*)d_in[9];
    const float* out_b      = (const float*)d_in[10];

    const size_t NE = (size_t)Bn * Hn * Ln;
    float* h  = (float*)d_out;                        // (B,L,H) final output only
    float* hT = (float*)d_ws;                         // (B,256,L) f32 residual stream
    unsigned short* yT = (unsigned short*)(hT + NE);  // (B,H,L) bf16 scan output

    const dim3 gg(256, 4), gb(256);

    // encoder: hT = (x @ enc_w^T + enc_b)^T
    mfma_gemm<DINn, false, true, false, false><<<gg, gb, 0, stream>>>(
        nullptr, x, enc_w, enc_b, nullptr, hT, nullptr);

    for (int i = 0; i < NLn; ++i) {
        s4_scan_kernel<<<dim3(Hn / 4, Bn), gb, 0, stream>>>(
            hT, yT,
            log_dt + (size_t)i * Hn,
            log_A_real + (size_t)i * Hn * N2n,
            A_imag + (size_t)i * Hn * N2n,
            C_re + (size_t)i * Hn * N2n,
            C_im + (size_t)i * Hn * N2n,
            D_skip + (size_t)i * Hn);
        const float* wlay = out_w + (size_t)i * 2 * Hn * Hn;
        const float* bl = out_b + (size_t)i * 2 * Hn;
        if (i == NLn - 1) {
            mfma_gemm<Hn, true, false, true, true><<<gg, gb, 0, stream>>>(
                yT, nullptr, wlay, bl, bl + Hn, hT, h);
        } else {
            mfma_gemm<Hn, true, false, true, false><<<gg, gb, 0, stream>>>(
                yT, nullptr, wlay, bl, bl + Hn, hT, nullptr);
        }
    }
}